// Round 1
// baseline (440.125 us; speedup 1.0000x reference)
//
#include <hip/hip_runtime.h>
#include <math.h>

namespace {
constexpr int DETN = 816;
constexpr int NVIEW = 720;
constexpr int NB = 8;
constexpr int IMGN = 512;
constexpr float PIXSZ = 0.5f;
constexpr float SID = 750.0f;
constexpr float SDD = 1250.0f;
constexpr float DBETA = 6.28318530717958647692f / 720.0f;

constexpr int XPAD = 1632;       // 407 left zeros + 816 data + 409 right zeros
constexpr int RPB = 5;           // rows per filter block
constexpr int T = 16;            // outputs per thread
constexpr int TPR = DETN / T;    // 51 threads per row
constexpr int ROWSTRIDE = 1736;  // > skew(1631)=1732

__device__ __forceinline__ int skew(int i) { return i + (i >> 4); }

// y[w] = sum_i x[w+i-407] * f[i]  (cross-correlation, zero-padded)
// then scale by cosw(w) * dbeta, store transposed: sino[v][w][b]
__global__ __launch_bounds__(256) void filt_kernel(
    const float* __restrict__ x, const float* __restrict__ filt,
    float* __restrict__ sino)
{
  __shared__ float xs[RPB * ROWSTRIDE];
  const int tid = threadIdx.x;
  const int blk = blockIdx.x;

  // stage RPB rows, zero-padded, skewed
  for (int p = tid; p < RPB * XPAD; p += 256) {
    int r = p / XPAD;
    int q = p - r * XPAD;
    int src = q - 407;
    float v = 0.0f;
    if (src >= 0 && src < DETN) v = x[(blk * RPB + r) * DETN + src];
    xs[r * ROWSTRIDE + skew(q)] = v;
  }
  __syncthreads();

  if (tid >= RPB * TPR) return;
  const int r = tid / TPR;
  const int t = tid - r * TPR;
  const int R = blk * RPB + r;
  const int b = R / NVIEW;          // x layout: [b][v][w]
  const int v = R - b * NVIEW;
  const float* __restrict__ xrow = &xs[r * ROWSTRIDE];
  const int w0 = t * T;

  float win[T], acc[T];
#pragma unroll
  for (int k = 0; k < T; ++k) { win[k] = xrow[skew(w0 + k)]; acc[k] = 0.0f; }

  for (int i = 0; i < DETN; i += T) {
#pragma unroll
    for (int u = 0; u < T; ++u) {
      const float fv = filt[i + u];       // wave-uniform -> s_load
#pragma unroll
      for (int k = 0; k < T; ++k)
        acc[k] = fmaf(win[(u + k) & (T - 1)], fv, acc[k]);
      win[u] = xrow[skew(w0 + i + u + T)];
    }
  }

#pragma unroll
  for (int k = 0; k < T; ++k) {
    const int w = w0 + k;
    const float ud = (float)w - 407.5f;
    const float cw = SID / sqrtf(SID * SID + ud * ud);
    sino[(v * DETN + w) * NB + b] = acc[k] * (cw * DBETA);
  }
}

__global__ __launch_bounds__(256) void bp_kernel(
    const float* __restrict__ sino, float* __restrict__ out)
{
  __shared__ float2 bt[NVIEW];
  const int tid = threadIdx.x;
  for (int v = tid; v < NVIEW; v += 256) {
    float s, c;
    sincosf((float)v * DBETA, &s, &c);
    bt[v] = make_float2(c, s);
  }
  __syncthreads();

  // wave = 8x8 pixel patch; block = 16x16 tile
  const int lane = tid & 63;
  const int wv = tid >> 6;
  const int px = ((wv & 1) << 3) | (lane & 7);
  const int py = ((wv >> 1) << 3) | (lane >> 3);
  const int j = (blockIdx.x << 4) + px;
  const int i = (blockIdx.y << 4) + py;
  const float X = ((float)j - 255.5f) * PIXSZ;
  const float Y = -(((float)i - 255.5f) * PIXSZ);

  float acc[NB];
#pragma unroll
  for (int b = 0; b < NB; ++b) acc[b] = 0.0f;

  const float4* __restrict__ s4 = (const float4*)sino;

  for (int v = 0; v < NVIEW; ++v) {
    const float2 cs = bt[v];
    const float cb = cs.x, sb = cs.y;
    const float xr = X * cb + Y * sb;
    const float L = SID + X * sb - Y * cb;   // SID - yr
    const float rL = __builtin_amdgcn_rcpf(L);
    const float tt = fmaf(SDD * xr, rL, 407.5f);
    const float m = SID * rL;
    const float w = m * m;                    // SID^2 / L^2
    float i0f = floorf(tt);
    i0f = fminf(fmaxf(i0f, 0.0f), 814.0f);
    const float frac = tt - i0f;
    const float a1 = w * frac;
    const float a0 = w - a1;                  // w*(1-frac)
    const int i0 = (int)i0f;
    const float4* p = s4 + (v * DETN + i0) * 2;
    const float4 q00 = p[0];  // det i0,   b0-3
    const float4 q01 = p[1];  // det i0,   b4-7
    const float4 q10 = p[2];  // det i0+1, b0-3
    const float4 q11 = p[3];  // det i0+1, b4-7
    acc[0] = fmaf(a0, q00.x, acc[0]);
    acc[1] = fmaf(a0, q00.y, acc[1]);
    acc[2] = fmaf(a0, q00.z, acc[2]);
    acc[3] = fmaf(a0, q00.w, acc[3]);
    acc[4] = fmaf(a0, q01.x, acc[4]);
    acc[5] = fmaf(a0, q01.y, acc[5]);
    acc[6] = fmaf(a0, q01.z, acc[6]);
    acc[7] = fmaf(a0, q01.w, acc[7]);
    acc[0] = fmaf(a1, q10.x, acc[0]);
    acc[1] = fmaf(a1, q10.y, acc[1]);
    acc[2] = fmaf(a1, q10.z, acc[2]);
    acc[3] = fmaf(a1, q10.w, acc[3]);
    acc[4] = fmaf(a1, q11.x, acc[4]);
    acc[5] = fmaf(a1, q11.y, acc[5]);
    acc[6] = fmaf(a1, q11.z, acc[6]);
    acc[7] = fmaf(a1, q11.w, acc[7]);
  }

#pragma unroll
  for (int b = 0; b < NB; ++b)
    out[(b * IMGN + i) * IMGN + j] = acc[b];
}

} // namespace

extern "C" void kernel_launch(void* const* d_in, const int* in_sizes, int n_in,
                              void* d_out, int out_size, void* d_ws, size_t ws_size,
                              hipStream_t stream) {
  const float* x = (const float*)d_in[0];
  const float* filt = (const float*)d_in[1];
  float* out = (float*)d_out;
  float* sino = (float*)d_ws;   // 720*816*8 floats = 18.8 MB

  filt_kernel<<<(NB * NVIEW) / RPB, 256, 0, stream>>>(x, filt, sino);
  bp_kernel<<<dim3(IMGN / 16, IMGN / 16), 256, 0, stream>>>(sino, out);
}

// Round 2
// 417.010 us; speedup vs baseline: 1.0554x; 1.0554x over previous
//
#include <hip/hip_runtime.h>
#include <math.h>

namespace {
constexpr int DETN = 816;
constexpr int NVIEW = 720;
constexpr int NB = 8;
constexpr int IMGN = 512;
constexpr float PIXSZ = 0.5f;
constexpr float SID = 750.0f;
constexpr float SDD = 1250.0f;
constexpr float DBETA = 6.28318530717958647692f / 720.0f;

constexpr int XPAD = 1632;       // 407 left zeros + 816 data + 409 right zeros
constexpr int RPB = 5;           // rows per filter block
constexpr int T = 16;            // outputs per thread
constexpr int TPR = DETN / T;    // 51 threads per row
constexpr int ROWSTRIDE = 1736;  // > skew(1631)=1732

constexpr int NSPLIT = 2;
constexpr int VH = NVIEW / NSPLIT;   // 360 views per half

__device__ __forceinline__ int skew(int i) { return i + (i >> 4); }

// Ramp filter: f[i] nonzero only for even i (odd d=i-407) plus center i=407.
// y[w] = sum_{even i} x[w+i-407]*f[i] + x[w]*f[407], scaled by cosw(w)*dbeta.
// Output transposed: sino[v][w][b]
__global__ __launch_bounds__(256) void filt_kernel(
    const float* __restrict__ x, const float* __restrict__ filt,
    float* __restrict__ sino)
{
  __shared__ float xs[RPB * ROWSTRIDE];
  const int tid = threadIdx.x;
  const int blk = blockIdx.x;

  // stage RPB rows, zero-padded, skewed
  for (int p = tid; p < RPB * XPAD; p += 256) {
    int r = p / XPAD;
    int q = p - r * XPAD;
    int src = q - 407;
    float v = 0.0f;
    if (src >= 0 && src < DETN) v = x[(blk * RPB + r) * DETN + src];
    xs[r * ROWSTRIDE + skew(q)] = v;
  }
  __syncthreads();

  if (tid >= RPB * TPR) return;
  const int r = tid / TPR;
  const int t = tid - r * TPR;
  const int R = blk * RPB + r;
  const int b = R / NVIEW;          // x layout: [b][v][w]
  const int v = R - b * NVIEW;
  const float* __restrict__ xrow = &xs[r * ROWSTRIDE];
  const int w0 = t * T;

  // window invariant: win[(2s+k)&15] = xs_padded[w0 + 2s + k], k=0..15
  float win[T], acc[T];
#pragma unroll
  for (int k = 0; k < T; ++k) { win[k] = xrow[skew(w0 + k)]; acc[k] = 0.0f; }

  // 408 even-tap steps, unrolled by 8 (2s mod 16 has period 8)
  for (int s8 = 0; s8 < 51; ++s8) {
#pragma unroll
    for (int u = 0; u < 8; ++u) {
      const int s = s8 * 8 + u;
      const float fv = filt[2 * s];          // wave-uniform -> s_load
#pragma unroll
      for (int k = 0; k < T; ++k)
        acc[k] = fmaf(win[(2 * u + k) & (T - 1)], fv, acc[k]);
      win[(2 * u) & 15] = xrow[skew(w0 + 2 * s + 16)];
      win[(2 * u + 1) & 15] = xrow[skew(w0 + 2 * s + 17)];
    }
  }

  // center tap
  const float fc = filt[407];
#pragma unroll
  for (int k = 0; k < T; ++k)
    acc[k] = fmaf(xrow[skew(w0 + k + 407)], fc, acc[k]);

#pragma unroll
  for (int k = 0; k < T; ++k) {
    const int w = w0 + k;
    const float ud = (float)w - 407.5f;
    const float cw = SID / sqrtf(SID * SID + ud * ud);
    sino[(v * DETN + w) * NB + b] = acc[k] * (cw * DBETA);
  }
}

__global__ __launch_bounds__(256, 8) void bp_kernel(
    const float* __restrict__ sino, float* __restrict__ out)
{
  __shared__ float2 bt[VH];
  const int tid = threadIdx.x;
  const int v0 = blockIdx.z * VH;
  for (int v = tid; v < VH; v += 256) {
    float s, c;
    sincosf((float)(v0 + v) * DBETA, &s, &c);
    bt[v] = make_float2(c, s);
  }
  __syncthreads();

  // wave = 8x8 pixel patch; block = 16x16 tile
  const int lane = tid & 63;
  const int wv = tid >> 6;
  const int px = ((wv & 1) << 3) | (lane & 7);
  const int py = ((wv >> 1) << 3) | (lane >> 3);
  const int j = (blockIdx.x << 4) + px;
  const int i = (blockIdx.y << 4) + py;
  const float X = ((float)j - 255.5f) * PIXSZ;
  const float Y = -(((float)i - 255.5f) * PIXSZ);

  float acc[NB];
#pragma unroll
  for (int b = 0; b < NB; ++b) acc[b] = 0.0f;

  const char* pv = (const char*)(sino + (size_t)v0 * DETN * NB);
  constexpr int VSTRIDE = DETN * NB * 4;   // bytes per view

  for (int it = 0; it < VH / 2; ++it) {
    // ---- view A geometry ----
    const float2 csA = bt[2 * it];
    const float xrA = fmaf(Y, csA.y, X * csA.x);
    const float LA = fmaf(-Y, csA.x, fmaf(X, csA.y, SID));
    const float rLA = __builtin_amdgcn_rcpf(LA);
    const float ttA = fmaf(SDD * xrA, rLA, 407.5f);
    const float mA = SID * rLA;
    const float wA = mA * mA;
    const int i0A = __float2int_rd(ttA);      // t in [97.5, 717.5] -> no clamp
    const float fracA = ttA - (float)i0A;
    const float a1A = wA * fracA;
    const float a0A = wA - a1A;
    // ---- view B geometry ----
    const float2 csB = bt[2 * it + 1];
    const float xrB = fmaf(Y, csB.y, X * csB.x);
    const float LB = fmaf(-Y, csB.x, fmaf(X, csB.y, SID));
    const float rLB = __builtin_amdgcn_rcpf(LB);
    const float ttB = fmaf(SDD * xrB, rLB, 407.5f);
    const float mB = SID * rLB;
    const float wB = mB * mB;
    const int i0B = __float2int_rd(ttB);
    const float fracB = ttB - (float)i0B;
    const float a1B = wB * fracB;
    const float a0B = wB - a1B;

    const float4* pA = (const float4*)(pv + (i0A << 5));
    const float4* pB = (const float4*)(pv + VSTRIDE + (i0B << 5));
    const float4 qA00 = pA[0];
    const float4 qA01 = pA[1];
    const float4 qA10 = pA[2];
    const float4 qA11 = pA[3];
    const float4 qB00 = pB[0];
    const float4 qB01 = pB[1];
    const float4 qB10 = pB[2];
    const float4 qB11 = pB[3];

    acc[0] = fmaf(a0A, qA00.x, acc[0]);
    acc[1] = fmaf(a0A, qA00.y, acc[1]);
    acc[2] = fmaf(a0A, qA00.z, acc[2]);
    acc[3] = fmaf(a0A, qA00.w, acc[3]);
    acc[4] = fmaf(a0A, qA01.x, acc[4]);
    acc[5] = fmaf(a0A, qA01.y, acc[5]);
    acc[6] = fmaf(a0A, qA01.z, acc[6]);
    acc[7] = fmaf(a0A, qA01.w, acc[7]);
    acc[0] = fmaf(a1A, qA10.x, acc[0]);
    acc[1] = fmaf(a1A, qA10.y, acc[1]);
    acc[2] = fmaf(a1A, qA10.z, acc[2]);
    acc[3] = fmaf(a1A, qA10.w, acc[3]);
    acc[4] = fmaf(a1A, qA11.x, acc[4]);
    acc[5] = fmaf(a1A, qA11.y, acc[5]);
    acc[6] = fmaf(a1A, qA11.z, acc[6]);
    acc[7] = fmaf(a1A, qA11.w, acc[7]);

    acc[0] = fmaf(a0B, qB00.x, acc[0]);
    acc[1] = fmaf(a0B, qB00.y, acc[1]);
    acc[2] = fmaf(a0B, qB00.z, acc[2]);
    acc[3] = fmaf(a0B, qB00.w, acc[3]);
    acc[4] = fmaf(a0B, qB01.x, acc[4]);
    acc[5] = fmaf(a0B, qB01.y, acc[5]);
    acc[6] = fmaf(a0B, qB01.z, acc[6]);
    acc[7] = fmaf(a0B, qB01.w, acc[7]);
    acc[0] = fmaf(a1B, qB10.x, acc[0]);
    acc[1] = fmaf(a1B, qB10.y, acc[1]);
    acc[2] = fmaf(a1B, qB10.z, acc[2]);
    acc[3] = fmaf(a1B, qB10.w, acc[3]);
    acc[4] = fmaf(a1B, qB11.x, acc[4]);
    acc[5] = fmaf(a1B, qB11.y, acc[5]);
    acc[6] = fmaf(a1B, qB11.z, acc[6]);
    acc[7] = fmaf(a1B, qB11.w, acc[7]);

    pv += 2 * VSTRIDE;
  }

#pragma unroll
  for (int b = 0; b < NB; ++b)
    atomicAdd(&out[(b * IMGN + i) * IMGN + j], acc[b]);
}

} // namespace

extern "C" void kernel_launch(void* const* d_in, const int* in_sizes, int n_in,
                              void* d_out, int out_size, void* d_ws, size_t ws_size,
                              hipStream_t stream) {
  const float* x = (const float*)d_in[0];
  const float* filt = (const float*)d_in[1];
  float* out = (float*)d_out;
  float* sino = (float*)d_ws;   // 720*816*8 floats = 18.8 MB

  hipMemsetAsync(out, 0, (size_t)out_size * sizeof(float), stream);
  filt_kernel<<<(NB * NVIEW) / RPB, 256, 0, stream>>>(x, filt, sino);
  bp_kernel<<<dim3(IMGN / 16, IMGN / 16, NSPLIT), 256, 0, stream>>>(sino, out);
}

// Round 3
// 316.146 us; speedup vs baseline: 1.3922x; 1.3190x over previous
//
#include <hip/hip_runtime.h>
#include <math.h>

namespace {
constexpr int DETN = 816;
constexpr int NVIEW = 720;
constexpr int NB = 8;
constexpr int IMGN = 512;
constexpr float PIXSZ = 0.5f;
constexpr float SID = 750.0f;
constexpr float SDD = 1250.0f;
constexpr float DBETA = 6.28318530717958647692f / 720.0f;

constexpr int XPAD = 1632;       // 407 left zeros + 816 data + 409 right zeros
constexpr int RPB = 5;           // rows per filter block
constexpr int T = 16;            // outputs per thread
constexpr int TPR = DETN / T;    // 51 threads per row
constexpr int ROWSTRIDE = 1736;  // > skew(1631)=1732

constexpr int NSPLIT = 2;
constexpr int VH = NVIEW / NSPLIT;   // 360 views per half

typedef __attribute__((ext_vector_type(8))) _Float16 h8;

__device__ __forceinline__ int skew(int i) { return i + (i >> 4); }

// Ramp filter: f[i] nonzero only for even i (odd d=i-407) plus center i=407.
// y[w] = sum_{even i} x[w+i-407]*f[i] + x[w]*f[407], scaled by cosw(w).
// (dbeta folded into bp epilogue.)  Output fp16, transposed: sino[v][w][b]
__global__ __launch_bounds__(256) void filt_kernel(
    const float* __restrict__ x, const float* __restrict__ filt,
    _Float16* __restrict__ sino)
{
  __shared__ float xs[RPB * ROWSTRIDE];
  const int tid = threadIdx.x;
  const int blk = blockIdx.x;

  // stage RPB rows, zero-padded, skewed
  for (int p = tid; p < RPB * XPAD; p += 256) {
    int r = p / XPAD;
    int q = p - r * XPAD;
    int src = q - 407;
    float v = 0.0f;
    if (src >= 0 && src < DETN) v = x[(blk * RPB + r) * DETN + src];
    xs[r * ROWSTRIDE + skew(q)] = v;
  }
  __syncthreads();

  if (tid >= RPB * TPR) return;
  const int r = tid / TPR;
  const int t = tid - r * TPR;
  const int R = blk * RPB + r;
  const int b = R / NVIEW;          // x layout: [b][v][w]
  const int v = R - b * NVIEW;
  const float* __restrict__ xrow = &xs[r * ROWSTRIDE];
  const int w0 = t * T;

  // window invariant: win[(2s+k)&15] = xs_padded[w0 + 2s + k], k=0..15
  float win[T], acc[T];
#pragma unroll
  for (int k = 0; k < T; ++k) { win[k] = xrow[skew(w0 + k)]; acc[k] = 0.0f; }

  // 408 even-tap steps, unrolled by 8 (2s mod 16 has period 8)
  for (int s8 = 0; s8 < 51; ++s8) {
#pragma unroll
    for (int u = 0; u < 8; ++u) {
      const int s = s8 * 8 + u;
      const float fv = filt[2 * s];          // wave-uniform -> s_load
#pragma unroll
      for (int k = 0; k < T; ++k)
        acc[k] = fmaf(win[(2 * u + k) & (T - 1)], fv, acc[k]);
      win[(2 * u) & 15] = xrow[skew(w0 + 2 * s + 16)];
      win[(2 * u + 1) & 15] = xrow[skew(w0 + 2 * s + 17)];
    }
  }

  // center tap
  const float fc = filt[407];
#pragma unroll
  for (int k = 0; k < T; ++k)
    acc[k] = fmaf(xrow[skew(w0 + k + 407)], fc, acc[k]);

#pragma unroll
  for (int k = 0; k < T; ++k) {
    const int w = w0 + k;
    const float ud = (float)w - 407.5f;
    const float cw = SID / sqrtf(SID * SID + ud * ud);
    sino[(v * DETN + w) * NB + b] = (_Float16)(acc[k] * cw);
  }
}

__global__ __launch_bounds__(256, 8) void bp_kernel(
    const _Float16* __restrict__ sino, float* __restrict__ out)
{
  __shared__ float2 bt[VH];
  const int tid = threadIdx.x;
  const int v0 = blockIdx.z * VH;
  for (int v = tid; v < VH; v += 256) {
    float s, c;
    sincosf((float)(v0 + v) * DBETA, &s, &c);
    bt[v] = make_float2(c, s);
  }
  __syncthreads();

  // wave = 8x8 pixel patch; block = 16x16 tile
  const int lane = tid & 63;
  const int wv = tid >> 6;
  const int px = ((wv & 1) << 3) | (lane & 7);
  const int py = ((wv >> 1) << 3) | (lane >> 3);
  const int j = (blockIdx.x << 4) + px;
  const int i = (blockIdx.y << 4) + py;
  const float X = ((float)j - 255.5f) * PIXSZ;
  const float Y = -(((float)i - 255.5f) * PIXSZ);

  float acc[NB];
#pragma unroll
  for (int b = 0; b < NB; ++b) acc[b] = 0.0f;

  const char* pv = (const char*)sino + (size_t)v0 * DETN * NB * 2;
  constexpr int VSTRIDE = DETN * NB * 2;   // bytes per view (fp16)

  for (int it = 0; it < VH / 2; ++it) {
    // ---- view A geometry ----
    const float2 csA = bt[2 * it];
    const float xrA = fmaf(Y, csA.y, X * csA.x);
    const float LA = fmaf(-Y, csA.x, fmaf(X, csA.y, SID));
    const float rLA = __builtin_amdgcn_rcpf(LA);
    const float ttA = fmaf(SDD * xrA, rLA, 407.5f);
    const float mA = SID * rLA;
    const float wA = mA * mA;
    const int i0A = __float2int_rd(ttA);      // t in [97.5, 717.5] -> no clamp
    const float fracA = ttA - (float)i0A;
    const float a1A = wA * fracA;
    const float a0A = wA - a1A;
    // ---- view B geometry ----
    const float2 csB = bt[2 * it + 1];
    const float xrB = fmaf(Y, csB.y, X * csB.x);
    const float LB = fmaf(-Y, csB.x, fmaf(X, csB.y, SID));
    const float rLB = __builtin_amdgcn_rcpf(LB);
    const float ttB = fmaf(SDD * xrB, rLB, 407.5f);
    const float mB = SID * rLB;
    const float wB = mB * mB;
    const int i0B = __float2int_rd(ttB);
    const float fracB = ttB - (float)i0B;
    const float a1B = wB * fracB;
    const float a0B = wB - a1B;

    // det i0 and i0+1 are 32 contiguous bytes -> 2x dwordx4 each view
    const h8* pA = (const h8*)(pv + (i0A << 4));
    const h8* pB = (const h8*)(pv + VSTRIDE + (i0B << 4));
    const h8 qA0 = pA[0];   // det i0,   b0-7
    const h8 qA1 = pA[1];   // det i0+1, b0-7
    const h8 qB0 = pB[0];
    const h8 qB1 = pB[1];

#pragma unroll
    for (int b = 0; b < NB; ++b) acc[b] = fmaf(a0A, (float)qA0[b], acc[b]);
#pragma unroll
    for (int b = 0; b < NB; ++b) acc[b] = fmaf(a1A, (float)qA1[b], acc[b]);
#pragma unroll
    for (int b = 0; b < NB; ++b) acc[b] = fmaf(a0B, (float)qB0[b], acc[b]);
#pragma unroll
    for (int b = 0; b < NB; ++b) acc[b] = fmaf(a1B, (float)qB1[b], acc[b]);

    pv += 2 * VSTRIDE;
  }

#pragma unroll
  for (int b = 0; b < NB; ++b)
    atomicAdd(&out[(b * IMGN + i) * IMGN + j], acc[b] * DBETA);
}

} // namespace

extern "C" void kernel_launch(void* const* d_in, const int* in_sizes, int n_in,
                              void* d_out, int out_size, void* d_ws, size_t ws_size,
                              hipStream_t stream) {
  const float* x = (const float*)d_in[0];
  const float* filt = (const float*)d_in[1];
  float* out = (float*)d_out;
  _Float16* sino = (_Float16*)d_ws;   // 720*816*8 halves = 9.4 MB

  hipMemsetAsync(out, 0, (size_t)out_size * sizeof(float), stream);
  filt_kernel<<<(NB * NVIEW) / RPB, 256, 0, stream>>>(x, filt, sino);
  bp_kernel<<<dim3(IMGN / 16, IMGN / 16, NSPLIT), 256, 0, stream>>>(sino, out);
}

// Round 5
// 285.243 us; speedup vs baseline: 1.5430x; 1.1083x over previous
//
#include <hip/hip_runtime.h>
#include <math.h>

namespace {
constexpr int DETN = 816;
constexpr int NVIEW = 720;
constexpr int NB = 8;
constexpr int IMGN = 512;
constexpr float PIXSZ = 0.5f;
constexpr float SID = 750.0f;
constexpr float SDD = 1250.0f;
constexpr float DBETA = 6.28318530717958647692f / 720.0f;

constexpr int XPAD = 1632;       // 407 left zeros + 816 data + 409 right zeros
constexpr int T = 16;            // outputs per thread
constexpr int TPR = DETN / T;    // 51 threads per row
constexpr int ROWSTRIDE = 1736;  // > skew(1631)=1732

constexpr int NSPLIT = 2;
constexpr int VH = NVIEW / NSPLIT;   // 360 views per half

typedef _Float16 h2 __attribute__((ext_vector_type(2)));

__device__ __forceinline__ int skew(int i) { return i + (i >> 4); }

// One block per view v; 8 rows = all batches. Ramp filter (odd-d taps + center),
// scale by cosw, then write PAIRED fp16: word[v][w][b] = (y[w][b], y[w+1][b]).
__global__ __launch_bounds__(512) void filt_kernel(
    const float* __restrict__ x, const float* __restrict__ filt,
    h2* __restrict__ sino2)
{
  __shared__ float xs[NB * ROWSTRIDE];   // 55.5 KB; reused as ys after conv
  const int tid = threadIdx.x;
  const int v = blockIdx.x;

  // stage 8 rows (one per batch) of view v, zero-padded, skewed
  for (int p = tid; p < NB * XPAD; p += 512) {
    int b = p / XPAD;
    int q = p - b * XPAD;
    int src = q - 407;
    float val = 0.0f;
    if (src >= 0 && src < DETN) val = x[(b * NVIEW + v) * DETN + src];
    xs[b * ROWSTRIDE + skew(q)] = val;
  }
  __syncthreads();

  const bool active = tid < NB * TPR;   // 408 compute threads
  const int b = tid / TPR;
  const int t = tid - b * TPR;
  const int w0 = t * T;
  float acc[T];

  if (active) {
    const float* __restrict__ xrow = &xs[b * ROWSTRIDE];
    float win[T];
#pragma unroll
    for (int k = 0; k < T; ++k) { win[k] = xrow[skew(w0 + k)]; acc[k] = 0.0f; }

    // 408 even-index taps (odd d), stepping 2; unroll 8 (2s mod 16 period 8)
    for (int s8 = 0; s8 < 51; ++s8) {
#pragma unroll
      for (int u = 0; u < 8; ++u) {
        const int s = s8 * 8 + u;
        const float fv = filt[2 * s];          // wave-uniform -> s_load
#pragma unroll
        for (int k = 0; k < T; ++k)
          acc[k] = fmaf(win[(2 * u + k) & (T - 1)], fv, acc[k]);
        win[(2 * u) & 15] = xrow[skew(w0 + 2 * s + 16)];
        win[(2 * u + 1) & 15] = xrow[skew(w0 + 2 * s + 17)];
      }
    }
    // center tap
    const float fc = filt[407];
#pragma unroll
    for (int k = 0; k < T; ++k)
      acc[k] = fmaf(xrow[skew(w0 + k + 407)], fc, acc[k]);

    // fold cos-weight
#pragma unroll
    for (int k = 0; k < T; ++k) {
      const float ud = (float)(w0 + k) - 407.5f;
      const float cw = SID / sqrtf(SID * SID + ud * ud);
      acc[k] *= cw;
    }
  }
  __syncthreads();          // all xs reads done -> reuse as ys

  float* ys = xs;           // [NB][DETN+1]
  if (active) {
#pragma unroll
    for (int k = 0; k < T; ++k) ys[b * (DETN + 1) + w0 + k] = acc[k];
    if (t == 0) ys[b * (DETN + 1) + DETN] = 0.0f;   // pad
  }
  __syncthreads();

  // cooperative pair-pack write, fully coalesced: word idx = w*8 + b
  h2* dst = sino2 + (size_t)v * DETN * NB;
  for (int idx = tid; idx < DETN * NB; idx += 512) {
    const int w = idx >> 3;
    const int bb = idx & 7;
    h2 hp;
    hp[0] = (_Float16)ys[bb * (DETN + 1) + w];
    hp[1] = (_Float16)ys[bb * (DETN + 1) + w + 1];
    dst[idx] = hp;
  }
}

__device__ __forceinline__ float dot2acc(h2 w, unsigned int q, float acc) {
  return __builtin_amdgcn_fdot2(w, __builtin_bit_cast(h2, q), acc, false);
}

__global__ __launch_bounds__(256, 8) void bp_kernel(
    const h2* __restrict__ sino2, float* __restrict__ out)
{
  __shared__ float2 bt[VH];
  const int tid = threadIdx.x;
  const int v0 = blockIdx.z * VH;
  for (int v = tid; v < VH; v += 256) {
    float s, c;
    sincosf((float)(v0 + v) * DBETA, &s, &c);
    bt[v] = make_float2(c, s);
  }
  __syncthreads();

  // wave = 8x8 pixel patch; block = 16x16 tile
  const int lane = tid & 63;
  const int wv = tid >> 6;
  const int px = ((wv & 1) << 3) | (lane & 7);
  const int py = ((wv >> 1) << 3) | (lane >> 3);
  const int j = (blockIdx.x << 4) + px;
  const int i = (blockIdx.y << 4) + py;
  const float X = ((float)j - 255.5f) * PIXSZ;
  const float Y = -(((float)i - 255.5f) * PIXSZ);

  float acc[NB];
#pragma unroll
  for (int b = 0; b < NB; ++b) acc[b] = 0.0f;

  const char* pv = (const char*)sino2 + (size_t)v0 * DETN * NB * 4;
  constexpr int VSTRIDE = DETN * NB * 4;   // bytes per view (paired fp16)

  for (int it = 0; it < VH / 2; ++it) {
    // ---- view A geometry ----
    const float2 csA = bt[2 * it];
    const float xrA = fmaf(Y, csA.y, X * csA.x);
    const float LA = fmaf(-Y, csA.x, fmaf(X, csA.y, SID));
    const float rLA = __builtin_amdgcn_rcpf(LA);
    const float ttA = fmaf(SDD * xrA, rLA, 407.5f);
    const float mA = SID * rLA;
    const float wA = mA * mA;
    const int i0A = __float2int_rd(ttA);      // t in [97.5, 717.5] -> no clamp
    const float fracA = ttA - (float)i0A;
    const float a1A = wA * fracA;
    const float a0A = wA - a1A;
    h2 wpA; wpA[0] = (_Float16)a0A; wpA[1] = (_Float16)a1A;
    // ---- view B geometry ----
    const float2 csB = bt[2 * it + 1];
    const float xrB = fmaf(Y, csB.y, X * csB.x);
    const float LB = fmaf(-Y, csB.x, fmaf(X, csB.y, SID));
    const float rLB = __builtin_amdgcn_rcpf(LB);
    const float ttB = fmaf(SDD * xrB, rLB, 407.5f);
    const float mB = SID * rLB;
    const float wB = mB * mB;
    const int i0B = __float2int_rd(ttB);
    const float fracB = ttB - (float)i0B;
    const float a1B = wB * fracB;
    const float a0B = wB - a1B;
    h2 wpB; wpB[0] = (_Float16)a0B; wpB[1] = (_Float16)a1B;

    // 32B per view: 8 pair-words (b0..b7) at det i0 -> 2x dwordx4
    const uint4* pA = (const uint4*)(pv + (i0A << 5));
    const uint4* pB = (const uint4*)(pv + VSTRIDE + (i0B << 5));
    const uint4 qA0 = pA[0];   // pairs b0-3
    const uint4 qA1 = pA[1];   // pairs b4-7
    const uint4 qB0 = pB[0];
    const uint4 qB1 = pB[1];

    acc[0] = dot2acc(wpA, qA0.x, acc[0]);
    acc[1] = dot2acc(wpA, qA0.y, acc[1]);
    acc[2] = dot2acc(wpA, qA0.z, acc[2]);
    acc[3] = dot2acc(wpA, qA0.w, acc[3]);
    acc[4] = dot2acc(wpA, qA1.x, acc[4]);
    acc[5] = dot2acc(wpA, qA1.y, acc[5]);
    acc[6] = dot2acc(wpA, qA1.z, acc[6]);
    acc[7] = dot2acc(wpA, qA1.w, acc[7]);

    acc[0] = dot2acc(wpB, qB0.x, acc[0]);
    acc[1] = dot2acc(wpB, qB0.y, acc[1]);
    acc[2] = dot2acc(wpB, qB0.z, acc[2]);
    acc[3] = dot2acc(wpB, qB0.w, acc[3]);
    acc[4] = dot2acc(wpB, qB1.x, acc[4]);
    acc[5] = dot2acc(wpB, qB1.y, acc[5]);
    acc[6] = dot2acc(wpB, qB1.z, acc[6]);
    acc[7] = dot2acc(wpB, qB1.w, acc[7]);

    pv += 2 * VSTRIDE;
  }

#pragma unroll
  for (int b = 0; b < NB; ++b)
    atomicAdd(&out[(b * IMGN + i) * IMGN + j], acc[b] * DBETA);
}

} // namespace

extern "C" void kernel_launch(void* const* d_in, const int* in_sizes, int n_in,
                              void* d_out, int out_size, void* d_ws, size_t ws_size,
                              hipStream_t stream) {
  const float* x = (const float*)d_in[0];
  const float* filt = (const float*)d_in[1];
  float* out = (float*)d_out;
  h2* sino2 = (h2*)d_ws;   // 720*816*8 paired-fp16 words = 18.8 MB

  (void)hipMemsetAsync(out, 0, (size_t)out_size * sizeof(float), stream);
  filt_kernel<<<NVIEW, 512, 0, stream>>>(x, filt, sino2);
  bp_kernel<<<dim3(IMGN / 16, IMGN / 16, NSPLIT), 256, 0, stream>>>(sino2, out);
}

// Round 7
// 268.449 us; speedup vs baseline: 1.6395x; 1.0626x over previous
//
#include <hip/hip_runtime.h>
#include <math.h>

namespace {
constexpr int DETN = 816;
constexpr int NVIEW = 720;
constexpr int NB = 8;
constexpr int IMGN = 512;
constexpr float PIXSZ = 0.5f;
constexpr float SID = 750.0f;
constexpr float SDD = 1250.0f;
constexpr float DBETA = 6.28318530717958647692f / 720.0f;

constexpr int XPAD = 1632;       // 407 left zeros + 816 data + 409 right zeros
constexpr int T = 16;            // outputs per thread
constexpr int TPR = DETN / T;    // 51 threads per row
constexpr int ROWSTRIDE = 1736;  // > skew(1631)=1732

constexpr int NSPLIT = 2;
constexpr int VH = NVIEW / NSPLIT;   // 360 views per half
constexpr int VP = VH / 2;           // 180 view-pairs

typedef _Float16 h2 __attribute__((ext_vector_type(2)));
typedef float f2 __attribute__((ext_vector_type(2)));

__device__ __forceinline__ int skew(int i) { return i + (i >> 4); }
__device__ __forceinline__ f2 fma2(f2 a, f2 b, f2 c) {
  return __builtin_elementwise_fma(a, b, c);
}
__device__ __forceinline__ h2 pack_h2(float a, float b) {
  return __builtin_bit_cast(h2, __builtin_amdgcn_cvt_pkrtz(a, b));
}

// One block per view v; 8 rows = all batches. Ramp filter (odd-d taps + center),
// scale by cosw, write PAIRED fp16: word[v][w][b] = (y[w][b], y[w+1][b]).
// Conv uses packed-f32: window pairs p[j]=(win[j],win[j+8]), acc2[k]=(y[k],y[k+8]).
__global__ __launch_bounds__(512) void filt_kernel(
    const float* __restrict__ x, const float* __restrict__ filt,
    h2* __restrict__ sino2)
{
  __shared__ float xs[NB * ROWSTRIDE];   // 55.5 KB; reused as ys after conv
  const int tid = threadIdx.x;
  const int v = blockIdx.x;

  // stage 8 rows (one per batch) of view v, zero-padded, skewed
  for (int p = tid; p < NB * XPAD; p += 512) {
    int b = p / XPAD;
    int q = p - b * XPAD;
    int src = q - 407;
    float val = 0.0f;
    if (src >= 0 && src < DETN) val = x[(b * NVIEW + v) * DETN + src];
    xs[b * ROWSTRIDE + skew(q)] = val;
  }
  __syncthreads();

  const bool active = tid < NB * TPR;   // 408 compute threads
  const int b = tid / TPR;
  const int t = tid - b * TPR;
  const int w0 = t * T;
  f2 acc2[8];

  if (active) {
    const float* __restrict__ xrow = &xs[b * ROWSTRIDE];
    f2 p[8];   // p[j] = (win[j], win[j+8]); win[i] = xs_padded[w0+2s+i]
#pragma unroll
    for (int k = 0; k < 8; ++k) {
      p[k].x = xrow[skew(w0 + k)];
      p[k].y = xrow[skew(w0 + k + 8)];
      acc2[k] = (f2){0.0f, 0.0f};
    }

    // 408 even-index taps (odd d), stepping 2; unroll 8 (2s mod 16 period 8)
    for (int s8 = 0; s8 < 51; ++s8) {
#pragma unroll
      for (int u = 0; u < 8; ++u) {
        const int s = s8 * 8 + u;
        const float fv = filt[2 * s];          // wave-uniform -> s_load
        const f2 fv2 = {fv, fv};
#pragma unroll
        for (int k = 0; k < 8; ++k) {
          const int idx = (2 * u + k) & 15;    // compile-time after unroll
          const f2 v2 = (idx < 8)
              ? p[idx]
              : __builtin_shufflevector(p[idx - 8], p[idx - 8], 1, 0);
          acc2[k] = fma2(v2, fv2, acc2[k]);
        }
        const float nv0 = xrow[skew(w0 + 2 * s + 16)];
        const float nv1 = xrow[skew(w0 + 2 * s + 17)];
        if (2 * u < 8) p[2 * u].x = nv0; else p[2 * u - 8].y = nv0;
        if (2 * u + 1 < 8) p[2 * u + 1].x = nv1; else p[2 * u - 7].y = nv1;
      }
    }
    // center tap
    const float fc = filt[407];
    const f2 fc2 = {fc, fc};
#pragma unroll
    for (int k = 0; k < 8; ++k) {
      f2 v2;
      v2.x = xrow[skew(w0 + k + 407)];
      v2.y = xrow[skew(w0 + k + 415)];
      acc2[k] = fma2(v2, fc2, acc2[k]);
    }
    // fold cos-weight
#pragma unroll
    for (int k = 0; k < 8; ++k) {
      const float udx = (float)(w0 + k) - 407.5f;
      const float udy = (float)(w0 + k + 8) - 407.5f;
      acc2[k].x *= SID / sqrtf(SID * SID + udx * udx);
      acc2[k].y *= SID / sqrtf(SID * SID + udy * udy);
    }
  }
  __syncthreads();          // all xs reads done -> reuse as ys

  float* ys = xs;           // [NB][DETN+1]
  if (active) {
#pragma unroll
    for (int k = 0; k < 8; ++k) {
      ys[b * (DETN + 1) + w0 + k] = acc2[k].x;
      ys[b * (DETN + 1) + w0 + k + 8] = acc2[k].y;
    }
    if (t == 0) ys[b * (DETN + 1) + DETN] = 0.0f;   // pad
  }
  __syncthreads();

  // cooperative pair-pack write, fully coalesced: word idx = w*8 + b
  h2* dst = sino2 + (size_t)v * DETN * NB;
  for (int idx = tid; idx < DETN * NB; idx += 512) {
    const int w = idx >> 3;
    const int bb = idx & 7;
    h2 hp;
    hp[0] = (_Float16)ys[bb * (DETN + 1) + w];
    hp[1] = (_Float16)ys[bb * (DETN + 1) + w + 1];
    dst[idx] = hp;
  }
}

__device__ __forceinline__ float dot2acc(h2 w, unsigned int q, float acc) {
  return __builtin_amdgcn_fdot2(w, __builtin_bit_cast(h2, q), acc, false);
}

__global__ __launch_bounds__(256, 8) void bp_kernel(
    const h2* __restrict__ sino2, float* __restrict__ out)
{
  // per view-pair tables: (cosA,cosB), (sinA,sinB), SDD-scaled versions
  __shared__ f2 cbp_t[VP], sbp_t[VP], csp_t[VP], ssp_t[VP];
  const int tid = threadIdx.x;
  const int v0 = blockIdx.z * VH;
  for (int it = tid; it < VP; it += 256) {
    float sA, cA, sB, cB;
    sincosf((float)(v0 + 2 * it) * DBETA, &sA, &cA);
    sincosf((float)(v0 + 2 * it + 1) * DBETA, &sB, &cB);
    cbp_t[it] = (f2){cA, cB};
    sbp_t[it] = (f2){sA, sB};
    csp_t[it] = (f2){SDD * cA, SDD * cB};
    ssp_t[it] = (f2){SDD * sA, SDD * sB};
  }
  __syncthreads();

  // wave = 8x8 pixel patch; block = 16x16 tile
  const int lane = tid & 63;
  const int wv = tid >> 6;
  const int px = ((wv & 1) << 3) | (lane & 7);
  const int py = ((wv >> 1) << 3) | (lane >> 3);
  const int j = (blockIdx.x << 4) + px;
  const int i = (blockIdx.y << 4) + py;
  const float X = ((float)j - 255.5f) * PIXSZ;
  const float Y = -(((float)i - 255.5f) * PIXSZ);
  const f2 X2 = {X, X};
  const f2 Y2 = {Y, Y};
  const f2 nY2 = {-Y, -Y};
  const f2 SID2 = {SID, SID};
  const f2 C4075 = {407.5f, 407.5f};

  float acc[NB];
#pragma unroll
  for (int b = 0; b < NB; ++b) acc[b] = 0.0f;

  const char* pv = (const char*)sino2 + (size_t)v0 * DETN * NB * 4;
  constexpr int VSTRIDE = DETN * NB * 4;   // bytes per view (paired fp16)

  for (int it = 0; it < VP; ++it) {
    const f2 cbp = cbp_t[it];
    const f2 sbp = sbp_t[it];
    const f2 csp = csp_t[it];
    const f2 ssp = ssp_t[it];

    const f2 num = fma2(Y2, ssp, X2 * csp);          // SDD * xr  (A,B)
    const f2 L = fma2(nY2, cbp, fma2(X2, sbp, SID2));
    const float rA = __builtin_amdgcn_rcpf(L.x);
    const float rB = __builtin_amdgcn_rcpf(L.y);
    const f2 rL = {rA, rB};
    const f2 tt = fma2(num, rL, C4075);              // t in [97.5, 717.5]
    const f2 m = SID2 * rL;
    const f2 w = m * m;
    const float i0fA = floorf(tt.x);
    const float i0fB = floorf(tt.y);
    const int i0A = (int)i0fA;
    const int i0B = (int)i0fB;
    const f2 frac = tt - (f2){i0fA, i0fB};
    const f2 a1 = w * frac;
    const f2 a0 = w - a1;
    const h2 wpA = pack_h2(a0.x, a1.x);
    const h2 wpB = pack_h2(a0.y, a1.y);

    // 32B per view: 8 pair-words (b0..b7) at det i0 -> 2x dwordx4
    const uint4* pA = (const uint4*)(pv + (i0A << 5));
    const uint4* pB = (const uint4*)(pv + VSTRIDE + (i0B << 5));
    const uint4 qA0 = pA[0];   // pairs b0-3
    const uint4 qA1 = pA[1];   // pairs b4-7
    const uint4 qB0 = pB[0];
    const uint4 qB1 = pB[1];

    acc[0] = dot2acc(wpA, qA0.x, acc[0]);
    acc[1] = dot2acc(wpA, qA0.y, acc[1]);
    acc[2] = dot2acc(wpA, qA0.z, acc[2]);
    acc[3] = dot2acc(wpA, qA0.w, acc[3]);
    acc[4] = dot2acc(wpA, qA1.x, acc[4]);
    acc[5] = dot2acc(wpA, qA1.y, acc[5]);
    acc[6] = dot2acc(wpA, qA1.z, acc[6]);
    acc[7] = dot2acc(wpA, qA1.w, acc[7]);

    acc[0] = dot2acc(wpB, qB0.x, acc[0]);
    acc[1] = dot2acc(wpB, qB0.y, acc[1]);
    acc[2] = dot2acc(wpB, qB0.z, acc[2]);
    acc[3] = dot2acc(wpB, qB0.w, acc[3]);
    acc[4] = dot2acc(wpB, qB1.x, acc[4]);
    acc[5] = dot2acc(wpB, qB1.y, acc[5]);
    acc[6] = dot2acc(wpB, qB1.z, acc[6]);
    acc[7] = dot2acc(wpB, qB1.w, acc[7]);

    pv += 2 * VSTRIDE;
  }

#pragma unroll
  for (int b = 0; b < NB; ++b)
    atomicAdd(&out[(b * IMGN + i) * IMGN + j], acc[b] * DBETA);
}

} // namespace

extern "C" void kernel_launch(void* const* d_in, const int* in_sizes, int n_in,
                              void* d_out, int out_size, void* d_ws, size_t ws_size,
                              hipStream_t stream) {
  const float* x = (const float*)d_in[0];
  const float* filt = (const float*)d_in[1];
  float* out = (float*)d_out;
  h2* sino2 = (h2*)d_ws;   // 720*816*8 paired-fp16 words = 18.8 MB

  (void)hipMemsetAsync(out, 0, (size_t)out_size * sizeof(float), stream);
  filt_kernel<<<NVIEW, 512, 0, stream>>>(x, filt, sino2);
  bp_kernel<<<dim3(IMGN / 16, IMGN / 16, NSPLIT), 256, 0, stream>>>(sino2, out);
}